// Round 1
// 1481.572 us; speedup vs baseline: 1.1349x; 1.1349x over previous
//
#include <hip/hip_runtime.h>
#include <hip/hip_bf16.h>
#include <math.h>

// ---------------- workspace layout (element offsets into float* ws) --------
// total ~571k floats = 2.29 MB
static constexpr size_t SIMS_OFF   = 0;         // 500000 float
static constexpr size_t Q_OFF      = 500736;    // 512 float
static constexpr size_t QN_OFF     = 501248;    // 512 float
static constexpr size_t HIST_OFF   = 501760;    // 4096 uint
static constexpr size_t COUNT_OFF  = 505856;    // 16 uint (count at [0])
static constexpr size_t THRESH_OFF = 505872;    // 16 float
static constexpr size_t CANDV_OFF  = 505888;    // 8192 float
static constexpr size_t CANDI_OFF  = 514080;    // 8192 int
static constexpr size_t SELI_OFF   = 522272;    // 32 int
static constexpr size_t SELV_OFF   = 522304;    // 32 float (unused downstream)
static constexpr size_t COMB_OFF   = 522336;    // 32*1024 float (16B aligned)
static constexpr size_t H_OFF      = 555104;    // 32*512 float

static constexpr int D_LAT   = 512;
static constexpr int D_QRY   = 768;
static constexpr int NBUCKET = 4096;
static constexpr int CAND_CAP= 8192;
static constexpr int K2      = 32;   // 2k
static constexpr int K1      = 16;   // k

// ---------------- 1a. query projection: q = Wp @ query + bp ----------------
// parallelized: one wave per output row (512 waves over 128 blocks) instead
// of a single block dragging 1.5 MB of Wp through one CU.
// Per-row arithmetic is IDENTICAL to the previous k_proj (same lane layout,
// same 12-term expression, same shfl_xor tree) -> bitwise-identical q.
__global__ __launch_bounds__(256) void k_proj_dot(
    const float* __restrict__ Wp, const float* __restrict__ query,
    const float* __restrict__ bp, float* __restrict__ q) {
  const int lane = threadIdx.x & 63;
  const int row  = (blockIdx.x * 256 + threadIdx.x) >> 6;   // 0..511

  const float4* q4 = (const float4*)query;
  float4 qq0 = q4[lane*3+0], qq1 = q4[lane*3+1], qq2 = q4[lane*3+2];

  const float4* w4 = (const float4*)(Wp + (size_t)row * D_QRY);
  float4 w0 = w4[lane*3+0], w1 = w4[lane*3+1], w2 = w4[lane*3+2];
  float acc = w0.x*qq0.x + w0.y*qq0.y + w0.z*qq0.z + w0.w*qq0.w
            + w1.x*qq1.x + w1.y*qq1.y + w1.z*qq1.z + w1.w*qq1.w
            + w2.x*qq2.x + w2.y*qq2.y + w2.z*qq2.z + w2.w*qq2.w;
#pragma unroll
  for (int off = 32; off; off >>= 1) acc += __shfl_xor(acc, off, 64);
  if (lane == 0) q[row] = acc + bp[row];
}

// ---------------- 1b. normalization: qn = q / (||q|| + 1e-8) ----------------
// same 512-thread tree reduction as the old fused kernel -> bitwise-identical.
__global__ __launch_bounds__(512) void k_norm(
    const float* __restrict__ q, float* __restrict__ qn) {
  __shared__ float s_red[512];
  const int tid = threadIdx.x;
  float v = q[tid];
  s_red[tid] = v * v;
  __syncthreads();
  for (int s = 256; s > 0; s >>= 1) {
    if (tid < s) s_red[tid] += s_red[tid + s];
    __syncthreads();
  }
  float nrm = sqrtf(s_red[0]) + 1e-8f;
  qn[tid] = v / nrm;
}

// ---------------- 2. cosine sims + histogram --------------------------------
// one wave per row; lane covers 8 floats (2 float4) of the 512-dim row
__global__ __launch_bounds__(256) void k_sims(
    const float* __restrict__ mem, const float* __restrict__ qn,
    float* __restrict__ sims, unsigned* __restrict__ ghist, int nrows) {
  __shared__ unsigned hist[NBUCKET];
  for (int i = threadIdx.x; i < NBUCKET; i += 256) hist[i] = 0;
  __syncthreads();

  const int lane   = threadIdx.x & 63;
  const int wave   = (blockIdx.x * 256 + threadIdx.x) >> 6;
  const int nwaves = (gridDim.x * 256) >> 6;

  const float4* qn4 = (const float4*)qn;
  float4 qa = qn4[lane*2], qb = qn4[lane*2+1];

  for (int row = wave; row < nrows; row += nwaves) {
    const float4* m4 = (const float4*)(mem + (size_t)row * D_LAT);
    float4 a = m4[lane*2], b = m4[lane*2+1];
    float dot = a.x*qa.x + a.y*qa.y + a.z*qa.z + a.w*qa.w
              + b.x*qb.x + b.y*qb.y + b.z*qb.z + b.w*qb.w;
    float ss  = a.x*a.x + a.y*a.y + a.z*a.z + a.w*a.w
              + b.x*b.x + b.y*b.y + b.z*b.z + b.w*b.w;
#pragma unroll
    for (int off = 32; off; off >>= 1) {
      dot += __shfl_xor(dot, off, 64);
      ss  += __shfl_xor(ss,  off, 64);
    }
    if (lane == 0) {
      float s = dot / (sqrtf(ss) + 1e-8f);
      sims[row] = s;
      int bkt = (int)((s + 1.0f) * 2048.0f);
      bkt = bkt < 0 ? 0 : (bkt > NBUCKET-1 ? NBUCKET-1 : bkt);
      atomicAdd(&hist[bkt], 1u);
    }
  }
  __syncthreads();
  for (int i = threadIdx.x; i < NBUCKET; i += 256)
    if (hist[i]) atomicAdd(&ghist[i], hist[i]);
}

// ---------------- 3. find value threshold covering top-32 -------------------
__global__ void k_thresh(const unsigned* __restrict__ ghist, float* __restrict__ thresh) {
  if (threadIdx.x == 0 && blockIdx.x == 0) {
    unsigned c = 0; int b = NBUCKET - 1;
    for (; b >= 0; --b) { c += ghist[b]; if (c >= (unsigned)K2) break; }
    if (b < 0) b = 0;
    thresh[0] = (float)b * (1.0f/2048.0f) - 1.0f - 1e-6f;
  }
}

// ---------------- 4. collect candidates >= threshold ------------------------
__global__ __launch_bounds__(256) void k_collect(
    const float* __restrict__ sims, const float* __restrict__ thresh,
    float* __restrict__ cv, int* __restrict__ ci, unsigned* __restrict__ count, int n) {
  float t = thresh[0];
  int stride = gridDim.x * 256;
  for (int i = blockIdx.x * 256 + threadIdx.x; i < n; i += stride) {
    float v = sims[i];
    if (v >= t) {
      unsigned p = atomicAdd(count, 1u);
      if (p < (unsigned)CAND_CAP) { cv[p] = v; ci[p] = i; }
    }
  }
}

// ---------------- 5. top-32 select (rank-based, jax tie-break) + gather -----
// Exact reimplementation of the serial successive-max: total order is
// (value desc, index asc). Pack into a 64-bit key:
//   key = (ordered_uint(value) << 32) | (0xFFFFFFFF - idx)
// Keys are unique (idx unique), so output position = #{keys > mine}.
// Parallel over 1024 threads; inner scan is an LDS broadcast read.
__global__ __launch_bounds__(1024) void k_select(
    const float* __restrict__ cv, const int* __restrict__ ci,
    const unsigned* __restrict__ count, const float* __restrict__ q,
    const float* __restrict__ mem, int* __restrict__ seli,
    float* __restrict__ comb) {
  __shared__ unsigned long long keys[CAND_CAP];
  __shared__ int s_idx[K2];
  const int tid = threadIdx.x;
  if (tid < K2) s_idx[tid] = 0;           // safety init (pre-first-sync)

  int n = (int)(*count);
  if (n > CAND_CAP) n = CAND_CAP;

  for (int j = tid; j < n; j += 1024) {
    unsigned u = __float_as_uint(cv[j]);
    u = (u & 0x80000000u) ? ~u : (u | 0x80000000u);   // monotone float->uint
    keys[j] = ((unsigned long long)u << 32)
            | (unsigned long long)(0xFFFFFFFFu - (unsigned)ci[j]);
  }
  __syncthreads();

  for (int j = tid; j < n; j += 1024) {
    unsigned long long k = keys[j];
    int r = 0;
    for (int i = 0; i < n; ++i) r += (keys[i] > k) ? 1 : 0;
    if (r < K2) { s_idx[r] = ci[j]; seli[r] = ci[j]; }
  }
  __syncthreads();

  // combined[c][0:512] = q ; combined[c][512:1024] = memory[idx_c]
  for (int t = tid; t < K2 * 2 * D_LAT; t += 1024) {
    int c = t >> 10, j = t & 1023;
    comb[t] = (j < D_LAT) ? q[j] : mem[(size_t)s_idx[c] * D_LAT + (j - D_LAT)];
  }
}

// ---------------- 6. rerank MLP layer 1: h = relu(comb @ W1^T + b1) ---------
// 16384 outputs (c,i); thread t: c = t&31, i = t>>5
__global__ __launch_bounds__(256) void k_mlp1(
    const float* __restrict__ comb, const float* __restrict__ W1,
    const float* __restrict__ b1, float* __restrict__ h) {
  int t = blockIdx.x * 256 + threadIdx.x;
  int c = t & 31, i = t >> 5;
  const float4* w4 = (const float4*)(W1 + (size_t)i * (2*D_LAT));
  const float4* c4 = (const float4*)(comb + (size_t)c * (2*D_LAT));
  float acc = 0.f;
#pragma unroll 8
  for (int j = 0; j < (2*D_LAT)/4; ++j) {
    float4 w = w4[j], x = c4[j];
    acc += w.x*x.x + w.y*x.y + w.z*x.z + w.w*x.w;
  }
  acc += b1[i];
  h[(size_t)c * D_LAT + i] = fmaxf(acc, 0.f);
}

// ---------------- 7. scores + top-16 + write output -------------------------
__global__ __launch_bounds__(64) void k_final(
    const float* __restrict__ h, const float* __restrict__ W2,
    const float* __restrict__ b2, const int* __restrict__ seli,
    float* __restrict__ out) {
  __shared__ float sc[K2];
  if (threadIdx.x < K2) {
    const float* hr = h + (size_t)threadIdx.x * D_LAT;
    float acc = 0.f;
    for (int i = 0; i < D_LAT; ++i) acc += hr[i] * W2[i];
    sc[threadIdx.x] = acc + b2[0];
  }
  __syncthreads();
  if (threadIdx.x == 0) {
    float pv = 1e30f; int pc = -1;
    for (int s = 0; s < K1; ++s) {
      float bv = -1e30f; int bc = 0;
      for (int c = 0; c < K2; ++c) {
        float v = sc[c];
        if (v > pv || (v == pv && c <= pc)) continue;
        if (v > bv) { bv = v; bc = c; }       // c ascending: ties keep lower c
      }
      out[s]      = bv;
      out[K1 + s] = (float)seli[bc];          // indices written as float32
      pv = bv; pc = bc;
    }
  }
}

// ---------------- launch -----------------------------------------------------
extern "C" void kernel_launch(void* const* d_in, const int* in_sizes, int n_in,
                              void* d_out, int out_size, void* d_ws, size_t ws_size,
                              hipStream_t stream) {
  (void)n_in; (void)out_size; (void)ws_size;
  const float* query  = (const float*)d_in[0];
  const float* memory = (const float*)d_in[1];
  const float* Wp     = (const float*)d_in[2];
  const float* bp     = (const float*)d_in[3];
  const float* W1     = (const float*)d_in[4];
  const float* b1     = (const float*)d_in[5];
  const float* W2     = (const float*)d_in[6];
  const float* b2     = (const float*)d_in[7];
  const int nrows = in_sizes[1] / D_LAT;   // 500000

  float*    ws    = (float*)d_ws;
  float*    sims  = ws + SIMS_OFF;
  float*    q     = ws + Q_OFF;
  float*    qn    = ws + QN_OFF;
  unsigned* hist  = (unsigned*)(ws + HIST_OFF);
  unsigned* count = (unsigned*)(ws + COUNT_OFF);
  float*    thr   = ws + THRESH_OFF;
  float*    candv = ws + CANDV_OFF;
  int*      candi = (int*)(ws + CANDI_OFF);
  int*      seli  = (int*)(ws + SELI_OFF);
  float*    comb  = ws + COMB_OFF;
  float*    h     = ws + H_OFF;
  float*    out   = (float*)d_out;

  hipMemsetAsync(hist, 0, (NBUCKET + 16) * sizeof(unsigned), stream);  // hist + count
  k_proj_dot<<<128,  256, 0, stream>>>(Wp, query, bp, q);
  k_norm    <<<1,    512, 0, stream>>>(q, qn);
  k_sims    <<<4096, 256, 0, stream>>>(memory, qn, sims, hist, nrows);
  k_thresh  <<<1,     64, 0, stream>>>(hist, thr);
  k_collect <<<256,  256, 0, stream>>>(sims, thr, candv, candi, count, nrows);
  k_select  <<<1,   1024, 0, stream>>>(candv, candi, count, q, memory, seli, comb);
  k_mlp1    <<<64,   256, 0, stream>>>(comb, W1, b1, h);
  k_final   <<<1,     64, 0, stream>>>(h, W2, b2, seli, out);
}